// Round 4
// baseline (240.454 us; speedup 1.0000x reference)
//
#include <hip/hip_runtime.h>
#include <math.h>

#define BEV_H 200
#define BEV_W 200
#define NPIX (BEV_H * BEV_W)
#define TILE_W 16
#define TILE_H 8
#define NTJ 13          // ceil(200/16)
#define NTI 25          // 200/8
#define BLOCK 128
#define NB 2
#define T_DEAD 1e-10f
#define NROUND 16       // covers G <= 2048
#define MAXG (NROUND * BLOCK)

// Phase 1: per-gaussian screen-space params + conservative bbox, once per
// gaussian (vs once per (tile,gaussian) = 325x in R1/R2).
__global__ __launch_bounds__(256) void precompute_kernel(
    const float* __restrict__ means3D, const float* __restrict__ cov3D,
    const float* __restrict__ opac, float4* __restrict__ params,  // 2 float4/g
    float4* __restrict__ bbox, int n /* NB*G */)
{
    const int idx = blockIdx.x * 256 + threadIdx.x;
    if (idx >= n) return;
    const float x = means3D[idx * 3 + 0], y = means3D[idx * 3 + 1];
    const float sxx = cov3D[idx * 6 + 0], sxy = cov3D[idx * 6 + 1],
                syy = cov3D[idx * 6 + 3];
    const float op = opac[idx];
    const float u = -2.0f * y + 100.0f;   // sh = BEV_H/H_METERS = 2
    const float v = -2.0f * x + 100.0f;
    const float c00 = 4.0f * syy + 0.3f;
    const float c01 = 4.0f * sxy;
    const float c11 = 4.0f * sxx + 0.3f;
    const float det = c00 * c11 - c01 * c01;
    float4 bb = make_float4(1e9f, -1e9f, 1e9f, -1e9f);   // always-miss
    float qa = 0.f, qb = 0.f, qc = 0.f, pth = 0.f;
    if (op > 0.05f && det > 0.0f) {
        const float inv = 1.0f / det;
        qa = -0.5f * (c11 * inv);
        qb = c01 * inv;                  // == -cB
        qc = -0.5f * (c00 * inv);
        const float L = logf(255.0f * op);   // > 0 since op > 0.05
        pth = -L;                        // alpha >= 1/255  <=>  power >= pth
        const float ru = sqrtf(2.0f * L * c00) + 0.01f;
        const float rv = sqrtf(2.0f * L * c11) + 0.01f;
        bb = make_float4(u - ru, u + ru, v - rv, v + rv);
    }
    params[idx * 2 + 0] = make_float4(u, v, qa, qb);
    params[idx * 2 + 1] = make_float4(qc, op, pth, 0.0f);
    bbox[idx] = bb;
}

// Phase 2: one block per (tile, batch).
// Scan: all NROUND ballots register-resident, 16 bbox loads in flight at
//   once, ONE barrier (R3 had 16 barrier'd rounds = ~24k serial cycles).
// Composite: distance-2 software pipeline, params+features prefetched
//   unconditionally into alternating register buffers (R3's per-iteration
//   dependent chain ds_read->readfirstlane->global was ~1150 cyc; measured
//   45 us fits 70 iters x 1150 + scan. Prefetch gives loads ~2 iterations
//   of flight time).
__global__ __launch_bounds__(BLOCK) void render_tile_kernel(
    const float* __restrict__ features, const float4* __restrict__ params,
    const float4* __restrict__ bbox, float* __restrict__ out, int G)
{
    __shared__ int slist[MAXG];
    __shared__ int cnt[2][NROUND];

    const int tid = threadIdx.x;
    const int b  = blockIdx.z;
    const int tj = blockIdx.x;
    const int ti = blockIdx.y;
    const int j = tj * TILE_W + (tid & (TILE_W - 1));
    const int i = ti * TILE_H + (tid / TILE_W);
    const float fi = (float)i, fj = (float)j;
    const bool in_range = (j < BEV_W);          // i always < 200
    const float ti_lo = (float)(ti * TILE_H), ti_hi = ti_lo + (TILE_H - 1);
    const float tj_lo = (float)(tj * TILE_W), tj_hi = tj_lo + (TILE_W - 1);
    const int gbase = b * G;
    const int lane = tid & 63, wid = tid >> 6;

    // ---- scan: register ballots, one barrier ----
    unsigned long long bal[NROUND];
#pragma unroll
    for (int r = 0; r < NROUND; ++r) {
        const int g = r * BLOCK + tid;
        bool keep = false;
        if (g < G) {
            const float4 bb = bbox[gbase + g];
            keep = (bb.y >= ti_lo) && (bb.x <= ti_hi) &&
                   (bb.w >= tj_lo) && (bb.z <= tj_hi);
        }
        bal[r] = __ballot(keep);
    }
    if (lane == 0) {
#pragma unroll
        for (int r = 0; r < NROUND; ++r) cnt[wid][r] = (int)__popcll(bal[r]);
    }
    __syncthreads();
    int total = 0;
#pragma unroll
    for (int r = 0; r < NROUND; ++r) {
        const int c0 = cnt[0][r];
        if ((bal[r] >> lane) & 1ull) {
            const int pre = (int)__popcll(bal[r] & ((1ull << lane) - 1ull));
            slist[total + (wid ? c0 : 0) + pre] = r * BLOCK + tid;
        }
        total += c0 + cnt[1][r];
    }
    __syncthreads();   // publish slist

    // ---- composite: distance-2 pipelined, barrier-free ----
    float acc[32];
#pragma unroll
    for (int d = 0; d < 32; ++d) acc[d] = 0.0f;
    float T = in_range ? 1.0f : 0.0f;   // pad lanes dead from the start

    float4 p0q[2], p1q[2], fq[2][8];
#pragma unroll
    for (int k0 = 0; k0 < 2; ++k0) {
        if (k0 < total) {
            const int g = __builtin_amdgcn_readfirstlane(slist[k0]);
            const float4* pp = params + (size_t)(gbase + g) * 2;
            p0q[k0] = pp[0];
            p1q[k0] = pp[1];
            const float4* fp = (const float4*)(features + (size_t)(gbase + g) * 32);
#pragma unroll
            for (int d = 0; d < 8; ++d) fq[k0][d] = fp[d];
        }
    }

#pragma unroll 2
    for (int k = 0; k < total; ++k) {
        const int q = k & 1;
        const float4 p0 = p0q[q];   // u v qa qb
        const float4 p1 = p1q[q];   // qc op pth -
        const float du = p0.x - fi;
        const float dv = p0.y - fj;
        const float power = p0.z * du * du + p1.x * dv * dv + p0.w * du * dv;
        if (T >= T_DEAD && power <= 0.0f && power >= p1.z) {
            const float alpha = fminf(0.99f, p1.y * __expf(power));
            const float w = alpha * T;
            T *= 1.0f - alpha;
#pragma unroll
            for (int d = 0; d < 8; ++d) {
                const float4 fv = fq[q][d];
                acc[4*d+0] = fmaf(w, fv.x, acc[4*d+0]);
                acc[4*d+1] = fmaf(w, fv.y, acc[4*d+1]);
                acc[4*d+2] = fmaf(w, fv.z, acc[4*d+2]);
                acc[4*d+3] = fmaf(w, fv.w, acc[4*d+3]);
            }
        }
        // refill slot q for iteration k+2 (issued after use; ~2 iterations
        // of flight time covers L2-hit latency)
        if (k + 2 < total) {
            const int gn = __builtin_amdgcn_readfirstlane(slist[k + 2]);
            const float4* pp = params + (size_t)(gbase + gn) * 2;
            p0q[q] = pp[0];
            p1q[q] = pp[1];
            const float4* fp = (const float4*)(features + (size_t)(gbase + gn) * 32);
#pragma unroll
            for (int d = 0; d < 8; ++d) fq[q][d] = fp[d];
        }
        if ((k & 7) == 7 && !__any(T >= T_DEAD)) break;
    }

    if (in_range) {
        const int p = i * BEV_W + j;
        float* ob = out + (size_t)b * 32 * NPIX + p;
#pragma unroll
        for (int d = 0; d < 32; ++d) ob[(size_t)d * NPIX] = acc[d];
    }
}

// num_gaussians = sum(op > 0.05) / B
__global__ __launch_bounds__(256) void count_kernel(
    const float* __restrict__ opac, float* __restrict__ out, int n, int out_idx)
{
    __shared__ float sdata[256];
    const int tid = threadIdx.x;
    float s = 0.0f;
    for (int idx = tid; idx < n; idx += 256)
        s += (opac[idx] > 0.05f) ? 1.0f : 0.0f;
    sdata[tid] = s;
    __syncthreads();
    for (int off = 128; off > 0; off >>= 1) {
        if (tid < off) sdata[tid] += sdata[tid + off];
        __syncthreads();
    }
    if (tid == 0) out[out_idx] = sdata[0] * (1.0f / NB);
}

extern "C" void kernel_launch(void* const* d_in, const int* in_sizes, int n_in,
                              void* d_out, int out_size, void* d_ws, size_t ws_size,
                              hipStream_t stream)
{
    const float* features = (const float*)d_in[0];
    const float* means3D  = (const float*)d_in[1];
    const float* cov3D    = (const float*)d_in[2];
    const float* opac     = (const float*)d_in[3];
    float* out = (float*)d_out;

    const int G = in_sizes[3] / NB;   // opacities is (B, G, 1)
    const int n = NB * G;

    float4* params = (float4*)d_ws;           // n * 2 float4
    float4* bbox   = params + (size_t)n * 2;  // n float4

    precompute_kernel<<<(n + 255) / 256, 256, 0, stream>>>(
        means3D, cov3D, opac, params, bbox, n);

    dim3 grid(NTJ, NTI, NB);
    render_tile_kernel<<<grid, BLOCK, 0, stream>>>(features, params, bbox, out, G);

    count_kernel<<<1, 256, 0, stream>>>(opac, out, n, NB * 32 * NPIX);
}

// Round 5
// 93.996 us; speedup vs baseline: 2.5581x; 2.5581x over previous
//
#include <hip/hip_runtime.h>
#include <math.h>

#define BEV_H 200
#define BEV_W 200
#define NPIX (BEV_H * BEV_W)
#define TILE_W 16
#define TILE_H 8
#define NTJ 13          // ceil(200/16)
#define NTI 25          // 200/8
#define BLOCK 128
#define NB 2
#define T_DEAD 1e-10f
#define NROUND 16       // covers G <= 2048
#define MAXG (NROUND * BLOCK)
#define KC 128          // kept-gaussian chunk staged in LDS

// Phase 1: per-gaussian screen params + conservative bbox, once per gaussian.
__global__ __launch_bounds__(256) void precompute_kernel(
    const float* __restrict__ means3D, const float* __restrict__ cov3D,
    const float* __restrict__ opac, float4* __restrict__ params,  // 2 float4/g
    float4* __restrict__ bbox, int n /* NB*G */)
{
    const int idx = blockIdx.x * 256 + threadIdx.x;
    if (idx >= n) return;
    const float x = means3D[idx * 3 + 0], y = means3D[idx * 3 + 1];
    const float sxx = cov3D[idx * 6 + 0], sxy = cov3D[idx * 6 + 1],
                syy = cov3D[idx * 6 + 3];
    const float op = opac[idx];
    const float u = -2.0f * y + 100.0f;   // sh = BEV_H/H_METERS = 2
    const float v = -2.0f * x + 100.0f;
    const float c00 = 4.0f * syy + 0.3f;
    const float c01 = 4.0f * sxy;
    const float c11 = 4.0f * sxx + 0.3f;
    const float det = c00 * c11 - c01 * c01;
    float4 bb = make_float4(1e9f, -1e9f, 1e9f, -1e9f);   // always-miss
    float qa = 0.f, qb = 0.f, qc = 0.f, pth = 0.f;
    if (op > 0.05f && det > 0.0f) {
        const float inv = 1.0f / det;
        qa = -0.5f * (c11 * inv);
        qb = c01 * inv;                  // == -cB
        qc = -0.5f * (c00 * inv);
        const float L = logf(255.0f * op);   // > 0 since op > 0.05
        pth = -L;                        // alpha >= 1/255  <=>  power >= pth
        const float ru = sqrtf(2.0f * L * c00) + 0.01f;
        const float rv = sqrtf(2.0f * L * c11) + 0.01f;
        bb = make_float4(u - ru, u + ru, v - rv, v + rv);
    }
    params[idx * 2 + 0] = make_float4(u, v, qa, qb);
    params[idx * 2 + 1] = make_float4(qc, op, pth, 0.0f);
    bbox[idx] = bb;
}

// Phase 2: one block per (tile, batch).
//   scan: register-resident ballots, 16 bbox loads in flight, 1 barrier.
//   stage: cooperative LDS gather of the KEPT gaussians' params+features
//     (independent parallel loads — R3/R4's bottleneck was these loads
//     sitting serially inside the T-dependent composite chain; R4's
//     register-prefetch fix spilled to scratch: 420 MB WRITE_SIZE).
//   composite: branchless (alpha=0 on miss), affine LDS addresses only —
//     compiler-pipelinable; the loop-carried dep is ~10 VALU ops on T.
__global__ __launch_bounds__(BLOCK) void render_tile_kernel(
    const float* __restrict__ features, const float4* __restrict__ params,
    const float4* __restrict__ bbox, float* __restrict__ out, int G)
{
    __shared__ int slist[MAXG];
    __shared__ int cnt[2][NROUND];
    __shared__ float pl[KC][8];
    __shared__ float fl[KC][32];

    const int tid = threadIdx.x;
    const int b  = blockIdx.z;
    const int tj = blockIdx.x;
    const int ti = blockIdx.y;
    const int j = tj * TILE_W + (tid & (TILE_W - 1));
    const int i = ti * TILE_H + (tid / TILE_W);
    const float fi = (float)i, fj = (float)j;
    const bool in_range = (j < BEV_W);          // i always < 200
    const float ti_lo = (float)(ti * TILE_H), ti_hi = ti_lo + (TILE_H - 1);
    const float tj_lo = (float)(tj * TILE_W), tj_hi = tj_lo + (TILE_W - 1);
    const int gbase = b * G;
    const int lane = tid & 63, wid = tid >> 6;

    // ---- scan: register ballots, one barrier ----
    unsigned long long bal[NROUND];
#pragma unroll
    for (int r = 0; r < NROUND; ++r) {
        const int g = r * BLOCK + tid;
        bool keep = false;
        if (g < G) {
            const float4 bb = bbox[gbase + g];
            keep = (bb.y >= ti_lo) && (bb.x <= ti_hi) &&
                   (bb.w >= tj_lo) && (bb.z <= tj_hi);
        }
        bal[r] = __ballot(keep);
    }
    if (lane == 0) {
#pragma unroll
        for (int r = 0; r < NROUND; ++r) cnt[wid][r] = (int)__popcll(bal[r]);
    }
    __syncthreads();
    int total = 0;
#pragma unroll
    for (int r = 0; r < NROUND; ++r) {
        const int c0 = cnt[0][r];
        if ((bal[r] >> lane) & 1ull) {
            const int pre = (int)__popcll(bal[r] & ((1ull << lane) - 1ull));
            slist[total + (wid ? c0 : 0) + pre] = r * BLOCK + tid;
        }
        total += c0 + cnt[1][r];
    }

    // ---- chunked: cooperative LDS staging + branchless composite ----
    float acc[32];
#pragma unroll
    for (int d = 0; d < 32; ++d) acc[d] = 0.0f;
    float T = in_range ? 1.0f : 0.0f;   // pad lanes dead from the start

    for (int k0 = 0; k0 < total; k0 += KC) {
        // Barrier: publishes slist (first iter), guards LDS reuse (later
        // iters), and gives whole-block early exit when all T dead.
        if (__syncthreads_and(T < T_DEAD)) break;
        const int nk = min(KC, total - k0);

        // stage params: 2 float4 per kept entry, independent gathers
        for (int idx = tid; idx < nk * 2; idx += BLOCK) {
            const int e = idx >> 1, h = idx & 1;
            const int g = slist[k0 + e];
            *(float4*)&pl[e][h * 4] = params[(size_t)(gbase + g) * 2 + h];
        }
        // stage features: 8 float4 per entry; 8 consecutive threads read one
        // gaussian's 128 contiguous bytes
        for (int idx = tid; idx < nk * 8; idx += BLOCK) {
            const int e = idx >> 3, q = idx & 7;
            const int g = slist[k0 + e];
            *(float4*)&fl[e][q * 4] =
                ((const float4*)(features + (size_t)(gbase + g) * 32))[q];
        }
        __syncthreads();

        for (int k = 0; k < nk; ++k) {
            const float4 p0 = *(const float4*)&pl[k][0];  // u v qa qb
            const float4 p1 = *(const float4*)&pl[k][4];  // qc op pth -
            const float du = p0.x - fi;
            const float dv = p0.y - fj;
            const float power = p0.z * du * du + p1.x * dv * dv + p0.w * du * dv;
            float alpha = fminf(0.99f, p1.y * __expf(power));
            alpha = (power <= 0.0f && power >= p1.z) ? alpha : 0.0f;
            const float w = alpha * T;
            T *= 1.0f - alpha;
#pragma unroll
            for (int d = 0; d < 8; ++d) {
                const float4 fv = *(const float4*)&fl[k][d * 4];
                acc[4*d+0] = fmaf(w, fv.x, acc[4*d+0]);
                acc[4*d+1] = fmaf(w, fv.y, acc[4*d+1]);
                acc[4*d+2] = fmaf(w, fv.z, acc[4*d+2]);
                acc[4*d+3] = fmaf(w, fv.w, acc[4*d+3]);
            }
            if ((k & 15) == 15 && !__any(T >= T_DEAD)) break;  // per-wave exit
        }
    }

    if (in_range) {
        const int p = i * BEV_W + j;
        float* ob = out + (size_t)b * 32 * NPIX + p;
#pragma unroll
        for (int d = 0; d < 32; ++d) ob[(size_t)d * NPIX] = acc[d];
    }
}

// num_gaussians = sum(op > 0.05) / B
__global__ __launch_bounds__(256) void count_kernel(
    const float* __restrict__ opac, float* __restrict__ out, int n, int out_idx)
{
    __shared__ float sdata[256];
    const int tid = threadIdx.x;
    float s = 0.0f;
    for (int idx = tid; idx < n; idx += 256)
        s += (opac[idx] > 0.05f) ? 1.0f : 0.0f;
    sdata[tid] = s;
    __syncthreads();
    for (int off = 128; off > 0; off >>= 1) {
        if (tid < off) sdata[tid] += sdata[tid + off];
        __syncthreads();
    }
    if (tid == 0) out[out_idx] = sdata[0] * (1.0f / NB);
}

extern "C" void kernel_launch(void* const* d_in, const int* in_sizes, int n_in,
                              void* d_out, int out_size, void* d_ws, size_t ws_size,
                              hipStream_t stream)
{
    const float* features = (const float*)d_in[0];
    const float* means3D  = (const float*)d_in[1];
    const float* cov3D    = (const float*)d_in[2];
    const float* opac     = (const float*)d_in[3];
    float* out = (float*)d_out;

    const int G = in_sizes[3] / NB;   // opacities is (B, G, 1)
    const int n = NB * G;

    float4* params = (float4*)d_ws;           // n * 2 float4
    float4* bbox   = params + (size_t)n * 2;  // n float4

    precompute_kernel<<<(n + 255) / 256, 256, 0, stream>>>(
        means3D, cov3D, opac, params, bbox, n);

    dim3 grid(NTJ, NTI, NB);
    render_tile_kernel<<<grid, BLOCK, 0, stream>>>(features, params, bbox, out, G);

    count_kernel<<<1, 256, 0, stream>>>(opac, out, n, NB * 32 * NPIX);
}